// Round 2
// baseline (2930.746 us; speedup 1.0000x reference)
//
#include <hip/hip_runtime.h>
#include <hip/hip_bf16.h>

#define M_TOK 16384        // 8 * 2048 tokens
#define DDIM 512
#define NCODES 8192
#define BM 64
#define BN 64
#define BK 32
#define LDA (BM + 4)
#define LDB (BN + 4)

// ---------------- c2[k] = ||codebook[k]||^2 ----------------
__global__ void c2_kernel(const float* __restrict__ cb, float* __restrict__ c2) {
    int row  = blockIdx.x * 4 + (threadIdx.x >> 6);   // 4 waves per block, 1 row per wave
    int lane = threadIdx.x & 63;
    const float* p = cb + (size_t)row * DDIM;
    float s = 0.f;
    #pragma unroll
    for (int d = 0; d < DDIM; d += 64) {
        float v = p[d + lane];
        s += v * v;
    }
    #pragma unroll
    for (int off = 32; off; off >>= 1) s += __shfl_down(s, off);
    if (lane == 0) c2[row] = s;
}

// ---------------- zero the loss accumulator ----------------
__global__ void zero_kernel(float* __restrict__ acc) {
    if (threadIdx.x == 0 && blockIdx.x == 0) *acc = 0.f;
}

// ---------------- argmin over codes (fp32 tiled GEMM + running min) --------
__launch_bounds__(256)
__global__ void argmin_kernel(const float* __restrict__ x, const float* __restrict__ cb,
                              const float* __restrict__ c2, int* __restrict__ idx_out) {
    __shared__ float a_s[BK][LDA];   // x tile, transposed [k][row]
    __shared__ float b_s[BK][LDB];   // code tile, transposed [k][col]

    const int tid = threadIdx.x;
    const int tx  = tid & 15;        // output column group (4 cols)
    const int ty  = tid >> 4;        // output row group (4 rows)
    const int row0 = blockIdx.x * BM;

    const int lr = tid >> 3;         // load row within tile (0..31)
    const int lc = (tid & 7) * 4;    // load col (float4 granularity, 0..28)

    float best[4];
    int   bidx[4];
    #pragma unroll
    for (int i = 0; i < 4; ++i) { best[i] = 3.0e38f; bidx[i] = 0; }

    for (int n0 = 0; n0 < NCODES; n0 += BN) {
        float acc[4][4];
        #pragma unroll
        for (int i = 0; i < 4; ++i)
            #pragma unroll
            for (int j = 0; j < 4; ++j) acc[i][j] = 0.f;

        for (int k0 = 0; k0 < DDIM; k0 += BK) {
            // stage x tile: rows row0..row0+63, cols k0..k0+31 (transposed into LDS)
            #pragma unroll
            for (int rr = 0; rr < BM; rr += 32) {
                int r = lr + rr;
                float4 va = *(const float4*)(x + (size_t)(row0 + r) * DDIM + k0 + lc);
                a_s[lc + 0][r] = va.x; a_s[lc + 1][r] = va.y;
                a_s[lc + 2][r] = va.z; a_s[lc + 3][r] = va.w;
                float4 vb = *(const float4*)(cb + (size_t)(n0 + r) * DDIM + k0 + lc);
                b_s[lc + 0][r] = vb.x; b_s[lc + 1][r] = vb.y;
                b_s[lc + 2][r] = vb.z; b_s[lc + 3][r] = vb.w;
            }
            __syncthreads();

            #pragma unroll
            for (int kk = 0; kk < BK; ++kk) {
                float4 af = *(const float4*)&a_s[kk][ty * 4];
                float4 bf = *(const float4*)&b_s[kk][tx * 4];
                float a[4] = {af.x, af.y, af.z, af.w};
                float b[4] = {bf.x, bf.y, bf.z, bf.w};
                #pragma unroll
                for (int i = 0; i < 4; ++i)
                    #pragma unroll
                    for (int j = 0; j < 4; ++j)
                        acc[i][j] += a[i] * b[j];
            }
            __syncthreads();
        }

        // score = ||c||^2 - 2 x.c ; running argmin (strict < keeps lowest index)
        #pragma unroll
        for (int j = 0; j < 4; ++j) {
            int col = n0 + tx * 4 + j;
            float c2v = c2[col];
            #pragma unroll
            for (int i = 0; i < 4; ++i) {
                float s = c2v - 2.0f * acc[i][j];
                if (s < best[i]) { best[i] = s; bidx[i] = col; }
            }
        }
    }

    // reduce across the 16 tx lanes sharing each row (within-wave, groups of 16)
    #pragma unroll
    for (int i = 0; i < 4; ++i) {
        float v = best[i];
        int   ix = bidx[i];
        #pragma unroll
        for (int off = 1; off < 16; off <<= 1) {
            float ov = __shfl_xor(v, off);
            int   oi = __shfl_xor(ix, off);
            if (ov < v || (ov == v && oi < ix)) { v = ov; ix = oi; }
        }
        if (tx == 0) idx_out[row0 + ty * 4 + i] = ix;
    }
}

// ---------------- gather codes, straight-through output, loss partials -----
__global__ void quantize_kernel(const float* __restrict__ x, const float* __restrict__ cb,
                                const int* __restrict__ idx, float* __restrict__ out,
                                float* __restrict__ acc) {
    __shared__ float red[4];
    float local = 0.f;
    const size_t total = (size_t)M_TOK * DDIM;
    for (size_t e = (size_t)blockIdx.x * blockDim.x + threadIdx.x; e < total;
         e += (size_t)gridDim.x * blockDim.x) {
        size_t t = e >> 9;
        int d = (int)(e & 511);
        int k = idx[t];
        float c  = cb[(size_t)k * DDIM + d];
        float xv = x[e];
        float diff = c - xv;                  // codes - x
        out[e] = xv + diff;                   // x + (codes - x)  (straight-through)
        local += diff * diff;
    }
    #pragma unroll
    for (int off = 32; off; off >>= 1) local += __shfl_down(local, off);
    int lane = threadIdx.x & 63, wv = threadIdx.x >> 6;
    if (lane == 0) red[wv] = local;
    __syncthreads();
    if (threadIdx.x == 0) {
        atomicAdd(acc, red[0] + red[1] + red[2] + red[3]);
    }
}

// ---------------- write indices (as fp32 values) + finalize loss -----------
__global__ void finalize_kernel(const int* __restrict__ idx, const float* __restrict__ acc,
                                float* __restrict__ out) {
    int t = blockIdx.x * blockDim.x + threadIdx.x;
    if (t < M_TOK) out[(size_t)M_TOK * DDIM + t] = (float)idx[t];
    if (t == 0) {
        float mean = (*acc) / (float)((size_t)M_TOK * DDIM);
        out[(size_t)M_TOK * DDIM + M_TOK] = 2.0f * mean;
    }
}

extern "C" void kernel_launch(void* const* d_in, const int* in_sizes, int n_in,
                              void* d_out, int out_size, void* d_ws, size_t ws_size,
                              hipStream_t stream) {
    const float* x  = (const float*)d_in[0];
    const float* cb = (const float*)d_in[1];
    float* out = (float*)d_out;

    int*   idx = (int*)d_ws;                                  // 16384 * 4 B
    float* c2  = (float*)((char*)d_ws + 65536);               //  8192 * 4 B
    float* acc = (float*)((char*)d_ws + 65536 + 32768);       //  1 float

    zero_kernel<<<1, 64, 0, stream>>>(acc);
    c2_kernel<<<NCODES / 4, 256, 0, stream>>>(cb, c2);
    argmin_kernel<<<M_TOK / BM, 256, 0, stream>>>(x, cb, c2, idx);
    quantize_kernel<<<2048, 256, 0, stream>>>(x, cb, idx, out, acc);
    finalize_kernel<<<(M_TOK + 255) / 256, 256, 0, stream>>>(idx, acc, out);
}

// Round 3
// 744.917 us; speedup vs baseline: 3.9343x; 3.9343x over previous
//
#include <hip/hip_runtime.h>
#include <hip/hip_bf16.h>

typedef unsigned short ushort_t;
typedef _Float16 f16;
typedef __attribute__((ext_vector_type(8))) _Float16 v8h;
typedef __attribute__((ext_vector_type(4))) float v4f;

#define M_TOK 16384        // 8 * 2048 tokens
#define DDIM 512
#define NCODES 8192
#define NTILE 64           // NCODES / 128
#define KCH 24             // (3*512)/64 k-chunks

// workspace layout (bytes)
#define OFF_AHI  0u
#define OFF_ALO  16777216u
#define OFF_BHI  33554432u
#define OFF_BLO  41943040u
#define OFF_PART 50331648u
#define OFF_IDX  67108864u
#define OFF_C2   67174400u
#define OFF_ACC  67207168u
#define WS_NEED  67207424u

// ---------------- helpers: top-2 with first-occurrence tie-break -----------
struct Top2 { float s1, s2; int i1, i2; };

__device__ __forceinline__ bool sless(float s, int i, float t, int j) {
    return s < t || (s == t && i < j);
}
__device__ __forceinline__ void t2_ins(Top2& t, float s, int i) {
    if (sless(s, i, t.s1, t.i1)) { t.s2 = t.s1; t.i2 = t.i1; t.s1 = s; t.i1 = i; }
    else if (sless(s, i, t.s2, t.i2)) { t.s2 = s; t.i2 = i; }
}
__device__ __forceinline__ void t2_mrg(Top2& t, const Top2& o) {
    t2_ins(t, o.s1, o.i1); t2_ins(t, o.s2, o.i2);
}

// ---------------- c2[k] = ||codebook[k]||^2 ----------------
__global__ void c2_kernel(const float* __restrict__ cb, float* __restrict__ c2) {
    int row  = blockIdx.x * 4 + (threadIdx.x >> 6);
    int lane = threadIdx.x & 63;
    const float* p = cb + (size_t)row * DDIM;
    float s = 0.f;
    #pragma unroll
    for (int d = 0; d < DDIM; d += 64) {
        float v = p[d + lane];
        s += v * v;
    }
    #pragma unroll
    for (int off = 32; off; off >>= 1) s += __shfl_down(s, off);
    if (lane == 0) c2[row] = s;
}

__global__ void zero_kernel(float* __restrict__ acc) {
    if (threadIdx.x == 0 && blockIdx.x == 0) *acc = 0.f;
}

// ---------------- fp32 -> f16 hi/lo split (8 elems/thread) ----------------
__global__ void split_kernel(const float* __restrict__ src, ushort_t* __restrict__ hi,
                             ushort_t* __restrict__ lo, int n8) {
    int i = blockIdx.x * blockDim.x + threadIdx.x;
    if (i >= n8) return;
    const float4* s4 = (const float4*)src + (size_t)i * 2;
    float4 a = s4[0], b = s4[1];
    float v[8] = {a.x, a.y, a.z, a.w, b.x, b.y, b.z, b.w};
    union { ushort_t u[8]; uint4 q; } H, L;
    #pragma unroll
    for (int j = 0; j < 8; ++j) {
        f16 h = (f16)v[j];
        float r = v[j] - (float)h;
        f16 lw = (f16)r;
        __builtin_memcpy(&H.u[j], &h, 2);
        __builtin_memcpy(&L.u[j], &lw, 2);
    }
    *(uint4*)(hi + (size_t)i * 8) = H.q;
    *(uint4*)(lo + (size_t)i * 8) = L.q;
}

// ---------------- MFMA f16 hi/lo GEMM with per-block top-2 epilogue -------
// S[m][n] = x[m].c[n] (split-f16 approx); score = c2[n] - 2 S. Block: 128x128.
__launch_bounds__(256)
__global__ void gemm_top2_kernel(const ushort_t* __restrict__ Ahi, const ushort_t* __restrict__ Alo,
                                 const ushort_t* __restrict__ Bhi, const ushort_t* __restrict__ Blo,
                                 const float* __restrict__ c2, float4* __restrict__ part) {
    __shared__ __align__(16) ushort_t Asb[128 * 64];
    __shared__ __align__(16) ushort_t Bsb[128 * 64];
    __shared__ float4 mergebuf[128][2];

    const int tid = threadIdx.x;
    const int wid = tid >> 6;
    const int l   = tid & 63;
    const int wr  = wid >> 1, wc = wid & 1;
    const int mtile = blockIdx.x >> 6;      // 0..127
    const int ntile = blockIdx.x & 63;      // 0..63
    const int row0 = mtile * 128;
    const int col0 = ntile * 128;

    const int lg = l >> 4;                  // lane group 0..3
    const int lc = l & 15;

    // staging geometry: each wave-load covers 8 rows (128 B/row), 16 B/lane
    const int srow  = l >> 3;               // row within 8-row group
    const int sslot = (l & 7) ^ srow;       // pre-swizzled source slot (G21)

    v4f acc[4][4];
    #pragma unroll
    for (int m = 0; m < 4; ++m)
        #pragma unroll
        for (int n = 0; n < 4; ++n) acc[m][n] = (v4f){0.f, 0.f, 0.f, 0.f};

    for (int kc = 0; kc < KCH; ++kc) {
        const int region = kc >> 3;                    // 0: hi.hi  1: hi.lo  2: lo.hi
        const int k0 = (kc & 7) * 64;
        const ushort_t* aptr = (region == 2) ? Alo : Ahi;
        const ushort_t* bptr = (region == 1) ? Blo : Bhi;

        __syncthreads();   // all waves done reading previous tile
        #pragma unroll
        for (int i = 0; i < 4; ++i) {
            int rr = (wid * 4 + i) * 8 + srow;
            const ushort_t* ga = aptr + (size_t)(row0 + rr) * DDIM + k0 + sslot * 8;
            __builtin_amdgcn_global_load_lds(
                (const __attribute__((address_space(1))) void*)ga,
                (__attribute__((address_space(3))) void*)&Asb[(wid * 4 + i) * 512], 16, 0, 0);
            const ushort_t* gb = bptr + (size_t)(col0 + rr) * DDIM + k0 + sslot * 8;
            __builtin_amdgcn_global_load_lds(
                (const __attribute__((address_space(1))) void*)gb,
                (__attribute__((address_space(3))) void*)&Bsb[(wid * 4 + i) * 512], 16, 0, 0);
        }
        __syncthreads();   // drains vmcnt + barrier

        #pragma unroll
        for (int ks = 0; ks < 2; ++ks) {
            v8h af[4], bf[4];
            #pragma unroll
            for (int m = 0; m < 4; ++m) {
                int row = wr * 64 + m * 16 + lc;
                int slot = ks * 4 + lg;
                int byteoff = row * 128 + ((slot ^ (row & 7)) * 16);
                af[m] = *(const v8h*)((const char*)Asb + byteoff);
            }
            #pragma unroll
            for (int n = 0; n < 4; ++n) {
                int row = wc * 64 + n * 16 + lc;
                int slot = ks * 4 + lg;
                int byteoff = row * 128 + ((slot ^ (row & 7)) * 16);
                bf[n] = *(const v8h*)((const char*)Bsb + byteoff);
            }
            #pragma unroll
            for (int m = 0; m < 4; ++m)
                #pragma unroll
                for (int n = 0; n < 4; ++n)
                    acc[m][n] = __builtin_amdgcn_mfma_f32_16x16x32_f16(af[m], bf[n], acc[m][n], 0, 0, 0);
        }
    }

    // ---- epilogue: per-row top-2 over this block's 128 columns ----
    // D layout: col = lc, row = lg*4 + j (verified m89/m91)
    #pragma unroll
    for (int m = 0; m < 4; ++m) {
        #pragma unroll
        for (int j = 0; j < 4; ++j) {
            int rloc = wr * 64 + m * 16 + lg * 4 + j;
            Top2 t; t.s1 = 3.0e38f; t.s2 = 3.0e38f; t.i1 = 0x7fffffff; t.i2 = 0x7fffffff;
            #pragma unroll
            for (int n = 0; n < 4; ++n) {
                int col = col0 + wc * 64 + n * 16 + lc;
                float s = c2[col] - 2.0f * acc[m][n][j];
                t2_ins(t, s, col);
            }
            #pragma unroll
            for (int off = 1; off < 16; off <<= 1) {
                Top2 o;
                o.s1 = __shfl_xor(t.s1, off); o.s2 = __shfl_xor(t.s2, off);
                o.i1 = __shfl_xor(t.i1, off); o.i2 = __shfl_xor(t.i2, off);
                t2_mrg(t, o);
            }
            if (lc == 0)
                mergebuf[rloc][wc] = make_float4(t.s1, t.s2, __int_as_float(t.i1), __int_as_float(t.i2));
        }
    }
    __syncthreads();
    if (tid < 128) {
        float4 p0 = mergebuf[tid][0], p1 = mergebuf[tid][1];
        Top2 t, o;
        t.s1 = p0.x; t.s2 = p0.y; t.i1 = __float_as_int(p0.z); t.i2 = __float_as_int(p0.w);
        o.s1 = p1.x; o.s2 = p1.y; o.i1 = __float_as_int(p1.z); o.i2 = __float_as_int(p1.w);
        t2_mrg(t, o);
        part[(size_t)(row0 + tid) * NTILE + ntile] =
            make_float4(t.s1, t.s2, __int_as_float(t.i1), __int_as_float(t.i2));
    }
}

// ---------------- merge 64 partials/token + exact double recheck ----------
__global__ void reduce_recheck_kernel(const float4* __restrict__ part,
                                      const float* __restrict__ x, const float* __restrict__ cb,
                                      int* __restrict__ idx) {
    int t = blockIdx.x * 4 + (threadIdx.x >> 6);
    int l = threadIdx.x & 63;
    float4 p = part[(size_t)t * NTILE + l];
    Top2 tp;
    tp.s1 = p.x; tp.s2 = p.y; tp.i1 = __float_as_int(p.z); tp.i2 = __float_as_int(p.w);
    #pragma unroll
    for (int off = 1; off < 64; off <<= 1) {
        Top2 o;
        o.s1 = __shfl_xor(tp.s1, off); o.s2 = __shfl_xor(tp.s2, off);
        o.i1 = __shfl_xor(tp.i1, off); o.i2 = __shfl_xor(tp.i2, off);
        t2_mrg(tp, o);
    }
    // exact double-precision distance for the two candidates
    int i1 = tp.i1, i2 = tp.i2;
    double d1 = 0.0, d2 = 0.0;
    const float* xp  = x + (size_t)t * DDIM + l * 8;
    const float* c1p = cb + (size_t)i1 * DDIM + l * 8;
    const float* c2p = cb + (size_t)i2 * DDIM + l * 8;
    #pragma unroll
    for (int j = 0; j < 8; ++j) {
        double xv = xp[j];
        double a = (double)c1p[j] - xv;
        double b = (double)c2p[j] - xv;
        d1 += a * a; d2 += b * b;
    }
    #pragma unroll
    for (int off = 1; off < 64; off <<= 1) {
        d1 += __shfl_xor(d1, off);
        d2 += __shfl_xor(d2, off);
    }
    int best = (d2 < d1 || (d2 == d1 && i2 < i1)) ? i2 : i1;
    if (l == 0) idx[t] = best;
}

// ---------------- fp32 fallback argmin (round-2 kernel) -------------------
#define BM 64
#define BN 64
#define BK 32
#define LDA (BM + 4)
#define LDB (BN + 4)
__launch_bounds__(256)
__global__ void argmin_kernel(const float* __restrict__ x, const float* __restrict__ cb,
                              const float* __restrict__ c2, int* __restrict__ idx_out) {
    __shared__ float a_s[BK][LDA];
    __shared__ float b_s[BK][LDB];
    const int tid = threadIdx.x;
    const int tx  = tid & 15;
    const int ty  = tid >> 4;
    const int row0 = blockIdx.x * BM;
    const int lr = tid >> 3;
    const int lcol = (tid & 7) * 4;
    float best[4]; int bidx[4];
    #pragma unroll
    for (int i = 0; i < 4; ++i) { best[i] = 3.0e38f; bidx[i] = 0; }
    for (int n0 = 0; n0 < NCODES; n0 += BN) {
        float acc[4][4];
        #pragma unroll
        for (int i = 0; i < 4; ++i)
            #pragma unroll
            for (int j = 0; j < 4; ++j) acc[i][j] = 0.f;
        for (int k0 = 0; k0 < DDIM; k0 += BK) {
            #pragma unroll
            for (int rr = 0; rr < BM; rr += 32) {
                int r = lr + rr;
                float4 va = *(const float4*)(x + (size_t)(row0 + r) * DDIM + k0 + lcol);
                a_s[lcol + 0][r] = va.x; a_s[lcol + 1][r] = va.y;
                a_s[lcol + 2][r] = va.z; a_s[lcol + 3][r] = va.w;
                float4 vb = *(const float4*)(cb + (size_t)(n0 + r) * DDIM + k0 + lcol);
                b_s[lcol + 0][r] = vb.x; b_s[lcol + 1][r] = vb.y;
                b_s[lcol + 2][r] = vb.z; b_s[lcol + 3][r] = vb.w;
            }
            __syncthreads();
            #pragma unroll
            for (int kk = 0; kk < BK; ++kk) {
                float4 af = *(const float4*)&a_s[kk][ty * 4];
                float4 bf = *(const float4*)&b_s[kk][tx * 4];
                float a[4] = {af.x, af.y, af.z, af.w};
                float b[4] = {bf.x, bf.y, bf.z, bf.w};
                #pragma unroll
                for (int i = 0; i < 4; ++i)
                    #pragma unroll
                    for (int j = 0; j < 4; ++j)
                        acc[i][j] += a[i] * b[j];
            }
            __syncthreads();
        }
        #pragma unroll
        for (int j = 0; j < 4; ++j) {
            int col = n0 + tx * 4 + j;
            float c2v = c2[col];
            #pragma unroll
            for (int i = 0; i < 4; ++i) {
                float s = c2v - 2.0f * acc[i][j];
                if (s < best[i]) { best[i] = s; bidx[i] = col; }
            }
        }
    }
    #pragma unroll
    for (int i = 0; i < 4; ++i) {
        float v = best[i]; int ix = bidx[i];
        #pragma unroll
        for (int off = 1; off < 16; off <<= 1) {
            float ov = __shfl_xor(v, off);
            int   oi = __shfl_xor(ix, off);
            if (ov < v || (ov == v && oi < ix)) { v = ov; ix = oi; }
        }
        if (tx == 0) idx_out[row0 + ty * 4 + i] = ix;
    }
}

// ---------------- gather codes, straight-through output, loss -------------
__global__ void quantize_kernel(const float* __restrict__ x, const float* __restrict__ cb,
                                const int* __restrict__ idx, float* __restrict__ out,
                                float* __restrict__ acc) {
    __shared__ float red[4];
    float local = 0.f;
    const size_t total = (size_t)M_TOK * DDIM;
    for (size_t e = (size_t)blockIdx.x * blockDim.x + threadIdx.x; e < total;
         e += (size_t)gridDim.x * blockDim.x) {
        size_t t = e >> 9;
        int d = (int)(e & 511);
        int k = idx[t];
        float c  = cb[(size_t)k * DDIM + d];
        float xv = x[e];
        float diff = c - xv;
        out[e] = xv + diff;
        local += diff * diff;
    }
    #pragma unroll
    for (int off = 32; off; off >>= 1) local += __shfl_down(local, off);
    int lane = threadIdx.x & 63, wv = threadIdx.x >> 6;
    if (lane == 0) red[wv] = local;
    __syncthreads();
    if (threadIdx.x == 0) atomicAdd(acc, red[0] + red[1] + red[2] + red[3]);
}

__global__ void finalize_kernel(const int* __restrict__ idx, const float* __restrict__ acc,
                                float* __restrict__ out) {
    int t = blockIdx.x * blockDim.x + threadIdx.x;
    if (t < M_TOK) out[(size_t)M_TOK * DDIM + t] = (float)idx[t];
    if (t == 0) {
        float mean = (*acc) / (float)((size_t)M_TOK * DDIM);
        out[(size_t)M_TOK * DDIM + M_TOK] = 2.0f * mean;
    }
}

extern "C" void kernel_launch(void* const* d_in, const int* in_sizes, int n_in,
                              void* d_out, int out_size, void* d_ws, size_t ws_size,
                              hipStream_t stream) {
    const float* x  = (const float*)d_in[0];
    const float* cb = (const float*)d_in[1];
    float* out = (float*)d_out;
    char* ws = (char*)d_ws;

    if (ws_size >= WS_NEED) {
        ushort_t* Ahi = (ushort_t*)(ws + OFF_AHI);
        ushort_t* Alo = (ushort_t*)(ws + OFF_ALO);
        ushort_t* Bhi = (ushort_t*)(ws + OFF_BHI);
        ushort_t* Blo = (ushort_t*)(ws + OFF_BLO);
        float4*   part = (float4*)(ws + OFF_PART);
        int*      idx = (int*)(ws + OFF_IDX);
        float*    c2  = (float*)(ws + OFF_C2);
        float*    acc = (float*)(ws + OFF_ACC);

        zero_kernel<<<1, 64, 0, stream>>>(acc);
        c2_kernel<<<NCODES / 4, 256, 0, stream>>>(cb, c2);
        split_kernel<<<(M_TOK * DDIM / 8) / 256, 256, 0, stream>>>(x, Ahi, Alo, M_TOK * DDIM / 8);
        split_kernel<<<(NCODES * DDIM / 8) / 256, 256, 0, stream>>>(cb, Bhi, Blo, NCODES * DDIM / 8);
        gemm_top2_kernel<<<(M_TOK / 128) * NTILE, 256, 0, stream>>>(Ahi, Alo, Bhi, Blo, c2, part);
        reduce_recheck_kernel<<<M_TOK / 4, 256, 0, stream>>>(part, x, cb, idx);
        quantize_kernel<<<2048, 256, 0, stream>>>(x, cb, idx, out, acc);
        finalize_kernel<<<(M_TOK + 255) / 256, 256, 0, stream>>>(idx, acc, out);
    } else {
        int*   idx = (int*)ws;
        float* c2  = (float*)(ws + 65536);
        float* acc = (float*)(ws + 65536 + 32768);
        zero_kernel<<<1, 64, 0, stream>>>(acc);
        c2_kernel<<<NCODES / 4, 256, 0, stream>>>(cb, c2);
        argmin_kernel<<<M_TOK / BM, 256, 0, stream>>>(x, cb, c2, idx);
        quantize_kernel<<<2048, 256, 0, stream>>>(x, cb, idx, out, acc);
        finalize_kernel<<<(M_TOK + 255) / 256, 256, 0, stream>>>(idx, acc, out);
    }
}

// Round 4
// 281.470 us; speedup vs baseline: 10.4123x; 2.6465x over previous
//
#include <hip/hip_runtime.h>
#include <hip/hip_bf16.h>

typedef unsigned short ushort_t;
typedef unsigned int u32;
typedef unsigned long long u64;
typedef _Float16 f16;
typedef __attribute__((ext_vector_type(8))) _Float16 v8h;
typedef __attribute__((ext_vector_type(4))) float v4f;

#define M_TOK 16384        // 8 * 2048 tokens
#define DDIM 512
#define NCODES 8192
#define NTILE 64           // NCODES / 128
#define KCH 8              // 512 / 64 k-chunks (hi-only)

// workspace layout (bytes)
#define OFF_AH   0u            // 16 MB  f16 hi(x)
#define OFF_BH   16777216u     //  8 MB  f16 hi(cb)
#define OFF_PART 25165824u     //  8 MB  u64 per (token, ntile)
#define OFF_IDX  33554432u     // 64 KB
#define OFF_C2   33619968u     // 32 KB
#define OFF_ACC  33652736u     //  4 B

// ---------------- c2[k] = ||codebook[k]||^2 ----------------
__global__ void c2_kernel(const float* __restrict__ cb, float* __restrict__ c2) {
    int row  = blockIdx.x * 4 + (threadIdx.x >> 6);
    int lane = threadIdx.x & 63;
    const float* p = cb + (size_t)row * DDIM;
    float s = 0.f;
    #pragma unroll
    for (int d = 0; d < DDIM; d += 64) {
        float v = p[d + lane];
        s += v * v;
    }
    #pragma unroll
    for (int off = 32; off; off >>= 1) s += __shfl_down(s, off);
    if (lane == 0) c2[row] = s;
}

__global__ void zero_kernel(float* __restrict__ acc) {
    if (threadIdx.x == 0 && blockIdx.x == 0) *acc = 0.f;
}

// ---------------- fp32 -> f16 (hi part only), 8 elems/thread --------------
__global__ void split_hi_kernel(const float* __restrict__ src, ushort_t* __restrict__ hi, int n8) {
    int i = blockIdx.x * blockDim.x + threadIdx.x;
    if (i >= n8) return;
    const float4* s4 = (const float4*)src + (size_t)i * 2;
    float4 a = s4[0], b = s4[1];
    float v[8] = {a.x, a.y, a.z, a.w, b.x, b.y, b.z, b.w};
    union { ushort_t u[8]; uint4 q; } H;
    #pragma unroll
    for (int j = 0; j < 8; ++j) {
        f16 h = (f16)v[j];
        __builtin_memcpy(&H.u[j], &h, 2);
    }
    *(uint4*)(hi + (size_t)i * 8) = H.q;
}

// ---------------- MFMA f16 GEMM, per-block top-1 (packed u64) -------------
// S[m][n] = hi(x[m]).hi(c[n]); score = c2[n] - 2 S.  Block: 128x128, 4 waves.
__launch_bounds__(256)
__global__ void gemm_top1_kernel(const ushort_t* __restrict__ Ah, const ushort_t* __restrict__ Bh,
                                 const float* __restrict__ c2, u64* __restrict__ part) {
    __shared__ __align__(16) ushort_t Asb[128 * 64];
    __shared__ __align__(16) ushort_t Bsb[128 * 64];
    __shared__ u64 mergebuf[128][2];

    const int tid = threadIdx.x;
    const int wid = tid >> 6;
    const int l   = tid & 63;
    const int wr  = wid >> 1, wc = wid & 1;
    const int mtile = blockIdx.x >> 6;      // 0..127
    const int ntile = blockIdx.x & 63;      // 0..63
    const int row0 = mtile * 128;
    const int col0 = ntile * 128;

    const int lg = l >> 4;                  // lane group 0..3
    const int lc = l & 15;

    // staging geometry (identical to the verified round-3 kernel)
    const int srow  = l >> 3;               // row within 8-row group
    const int sslot = (l & 7) ^ srow;       // pre-swizzled source slot (G21)

    v4f acc[4][4];
    #pragma unroll
    for (int m = 0; m < 4; ++m)
        #pragma unroll
        for (int n = 0; n < 4; ++n) acc[m][n] = (v4f){0.f, 0.f, 0.f, 0.f};

    for (int kc = 0; kc < KCH; ++kc) {
        const int k0 = kc * 64;

        __syncthreads();   // all waves done reading previous tile
        #pragma unroll
        for (int i = 0; i < 4; ++i) {
            int rr = (wid * 4 + i) * 8 + srow;
            const ushort_t* ga = Ah + (size_t)(row0 + rr) * DDIM + k0 + sslot * 8;
            __builtin_amdgcn_global_load_lds(
                (const __attribute__((address_space(1))) void*)ga,
                (__attribute__((address_space(3))) void*)&Asb[(wid * 4 + i) * 512], 16, 0, 0);
            const ushort_t* gb = Bh + (size_t)(col0 + rr) * DDIM + k0 + sslot * 8;
            __builtin_amdgcn_global_load_lds(
                (const __attribute__((address_space(1))) void*)gb,
                (__attribute__((address_space(3))) void*)&Bsb[(wid * 4 + i) * 512], 16, 0, 0);
        }
        __syncthreads();   // drains vmcnt + barrier

        #pragma unroll
        for (int ks = 0; ks < 2; ++ks) {
            v8h af[4], bf[4];
            #pragma unroll
            for (int m = 0; m < 4; ++m) {
                int row = wr * 64 + m * 16 + lc;
                int slot = ks * 4 + lg;
                int byteoff = row * 128 + ((slot ^ (row & 7)) * 16);
                af[m] = *(const v8h*)((const char*)Asb + byteoff);
            }
            #pragma unroll
            for (int n = 0; n < 4; ++n) {
                int row = wc * 64 + n * 16 + lc;
                int slot = ks * 4 + lg;
                int byteoff = row * 128 + ((slot ^ (row & 7)) * 16);
                bf[n] = *(const v8h*)((const char*)Bsb + byteoff);
            }
            #pragma unroll
            for (int m = 0; m < 4; ++m)
                #pragma unroll
                for (int n = 0; n < 4; ++n)
                    acc[m][n] = __builtin_amdgcn_mfma_f32_16x16x32_f16(af[m], bf[n], acc[m][n], 0, 0, 0);
        }
    }

    // ---- epilogue: per-row min over this block's 128 columns, packed u64 ----
    // D layout: col = lc, row = lg*4 + j (verified m89/m91 + round-3 pass)
    float c2v[4];
    #pragma unroll
    for (int n = 0; n < 4; ++n) c2v[n] = c2[col0 + wc * 64 + n * 16 + lc];

    #pragma unroll
    for (int m = 0; m < 4; ++m) {
        #pragma unroll
        for (int j = 0; j < 4; ++j) {
            int rloc = wr * 64 + m * 16 + lg * 4 + j;
            u64 best = ~0ull;
            #pragma unroll
            for (int n = 0; n < 4; ++n) {
                float s = c2v[n] - 2.0f * acc[m][n][j];
                u32 b = __float_as_uint(s);
                b = (b & 0x80000000u) ? ~b : (b | 0x80000000u);   // monotone float->u32
                int col = col0 + wc * 64 + n * 16 + lc;
                u64 key = ((u64)b << 32) | (u32)col;              // low bits: index tie-break
                best = key < best ? key : best;
            }
            #pragma unroll
            for (int off = 1; off < 16; off <<= 1) {
                u64 o = __shfl_xor(best, off);
                best = o < best ? o : best;
            }
            if (lc == 0) mergebuf[rloc][wc] = best;
        }
    }
    __syncthreads();
    if (tid < 128) {
        u64 a = mergebuf[tid][0], b = mergebuf[tid][1];
        part[(size_t)(row0 + tid) * NTILE + ntile] = a < b ? a : b;
    }
}

// ---------------- merge 64 block winners -> top-4 + exact fp64 recheck ----
__global__ void reduce_recheck_kernel(const u64* __restrict__ part,
                                      const float* __restrict__ x, const float* __restrict__ cb,
                                      int* __restrict__ idx) {
    int t = blockIdx.x * 4 + (threadIdx.x >> 6);
    int l = threadIdx.x & 63;
    u64 k = part[(size_t)t * NTILE + l];

    int cand[4];
    #pragma unroll
    for (int c = 0; c < 4; ++c) {
        u64 m = k;
        #pragma unroll
        for (int off = 1; off < 64; off <<= 1) {
            u64 o = __shfl_xor(m, off);
            m = o < m ? o : m;
        }
        cand[c] = (int)(u32)(m & 0xffffffffull);
        if (k == m) k = ~0ull;        // keys unique (distinct cols) -> removes one lane
    }

    // exact double-precision distances for the 4 candidates
    const float* xp = x + (size_t)t * DDIM + l * 8;
    float xv[8];
    #pragma unroll
    for (int j = 0; j < 8; ++j) xv[j] = xp[j];

    double d[4];
    #pragma unroll
    for (int c = 0; c < 4; ++c) {
        const float* cp = cb + (size_t)cand[c] * DDIM + l * 8;
        double s = 0.0;
        #pragma unroll
        for (int j = 0; j < 8; ++j) {
            double a = (double)cp[j] - (double)xv[j];
            s += a * a;
        }
        d[c] = s;
    }
    #pragma unroll
    for (int c = 0; c < 4; ++c) {
        #pragma unroll
        for (int off = 1; off < 64; off <<= 1) d[c] += __shfl_xor(d[c], off);
    }

    double bd = d[0]; int bi = cand[0];
    #pragma unroll
    for (int c = 1; c < 4; ++c)
        if (d[c] < bd || (d[c] == bd && cand[c] < bi)) { bd = d[c]; bi = cand[c]; }
    if (l == 0) idx[t] = bi;
}

// ---------------- gather codes, straight-through output, loss -------------
__global__ void quantize_kernel(const float* __restrict__ x, const float* __restrict__ cb,
                                const int* __restrict__ idx, float* __restrict__ out,
                                float* __restrict__ acc) {
    __shared__ float red[4];
    float local = 0.f;
    const size_t total = (size_t)M_TOK * DDIM;
    for (size_t e = (size_t)blockIdx.x * blockDim.x + threadIdx.x; e < total;
         e += (size_t)gridDim.x * blockDim.x) {
        size_t t = e >> 9;
        int d = (int)(e & 511);
        int k = idx[t];
        float c  = cb[(size_t)k * DDIM + d];
        float xv = x[e];
        float diff = c - xv;
        out[e] = xv + diff;
        local += diff * diff;
    }
    #pragma unroll
    for (int off = 32; off; off >>= 1) local += __shfl_down(local, off);
    int lane = threadIdx.x & 63, wv = threadIdx.x >> 6;
    if (lane == 0) red[wv] = local;
    __syncthreads();
    if (threadIdx.x == 0) atomicAdd(acc, red[0] + red[1] + red[2] + red[3]);
}

__global__ void finalize_kernel(const int* __restrict__ idx, const float* __restrict__ acc,
                                float* __restrict__ out) {
    int t = blockIdx.x * blockDim.x + threadIdx.x;
    if (t < M_TOK) out[(size_t)M_TOK * DDIM + t] = (float)idx[t];
    if (t == 0) {
        float mean = (*acc) / (float)((size_t)M_TOK * DDIM);
        out[(size_t)M_TOK * DDIM + M_TOK] = 2.0f * mean;
    }
}

extern "C" void kernel_launch(void* const* d_in, const int* in_sizes, int n_in,
                              void* d_out, int out_size, void* d_ws, size_t ws_size,
                              hipStream_t stream) {
    const float* x  = (const float*)d_in[0];
    const float* cb = (const float*)d_in[1];
    float* out = (float*)d_out;
    char* ws = (char*)d_ws;

    ushort_t* Ah  = (ushort_t*)(ws + OFF_AH);
    ushort_t* Bh  = (ushort_t*)(ws + OFF_BH);
    u64*      part = (u64*)(ws + OFF_PART);
    int*      idx = (int*)(ws + OFF_IDX);
    float*    c2  = (float*)(ws + OFF_C2);
    float*    acc = (float*)(ws + OFF_ACC);

    zero_kernel<<<1, 64, 0, stream>>>(acc);
    c2_kernel<<<NCODES / 4, 256, 0, stream>>>(cb, c2);
    split_hi_kernel<<<(M_TOK * DDIM / 8) / 256, 256, 0, stream>>>(x, Ah, M_TOK * DDIM / 8);
    split_hi_kernel<<<(NCODES * DDIM / 8) / 256, 256, 0, stream>>>(cb, Bh, NCODES * DDIM / 8);
    gemm_top1_kernel<<<(M_TOK / 128) * NTILE, 256, 0, stream>>>(Ah, Bh, c2, part);
    reduce_recheck_kernel<<<M_TOK / 4, 256, 0, stream>>>(part, x, cb, idx);
    quantize_kernel<<<2048, 256, 0, stream>>>(x, cb, idx, out, acc);
    finalize_kernel<<<(M_TOK + 255) / 256, 256, 0, stream>>>(idx, acc, out);
}